// Round 14
// baseline (952.115 us; speedup 1.0000x reference)
//
#include <hip/hip_runtime.h>
#include <stdint.h>
#include <math.h>

#define B_ 2
#define S_ 2048
#define H_ 4096
#define NH_ 32
#define HD_ 128
#define EL_ 16777216L  // 4096*4096

using s16x8 = __attribute__((ext_vector_type(8))) short;
using f32x4 = __attribute__((ext_vector_type(4))) float;

__device__ __forceinline__ unsigned short f2b(float f) {
  union { float f; unsigned u; } v; v.f = f;
  unsigned r = v.u + 0x7FFFu + ((v.u >> 16) & 1u);
  return (unsigned short)(r >> 16);
}
__device__ __forceinline__ unsigned short f2b_trunc(float f) {
  union { float f; unsigned u; } v; v.f = f;
  return (unsigned short)(v.u >> 16);
}
__device__ __forceinline__ float b2f(unsigned short h) {
  union { unsigned u; float f; } v; v.u = ((unsigned)h) << 16;
  return v.f;
}

__device__ __forceinline__ void async_cp16(const void* g, void* l) {
  __builtin_amdgcn_global_load_lds(
      (__attribute__((address_space(1))) void*)(void*)g,
      (__attribute__((address_space(3))) void*)l, 16, 0, 0);
}

#define MFMA16(a, b, c) __builtin_amdgcn_mfma_f32_16x16x32_bf16((a), (b), (c), 0, 0, 0)
#define BARRIER() asm volatile("s_barrier" ::: "memory")

// ---------------- cast fp32 -> bf16 ----------------
__global__ void cast_f32_bf16(const float* __restrict__ in,
                              unsigned short* __restrict__ out, long n) {
  long i = ((long)blockIdx.x * 256 + threadIdx.x) * 4;
  if (i >= n) return;
  const float4 v = *(const float4*)(in + i);
  ushort4 o;
  o.x = f2b(v.x); o.y = f2b(v.y); o.z = f2b(v.z); o.w = f2b(v.w);
  *(ushort4*)(out + i) = o;
}

// ------- transpose+cast (vectorized): in (rows x in_stride fp32) -> out (cols x 4096) bf16 transposed -------
__global__ void transpose_cast_4096(const float* __restrict__ in,
                                    unsigned short* __restrict__ out, int in_stride) {
  __shared__ unsigned tile[64][33];  // [out_row c][row_pair p]: lo=bf16(2p), hi=bf16(2p+1)
  const int t = threadIdx.x;
  const int c0 = blockIdx.x * 64;
  const int r0 = blockIdx.y * 64;
  const int l16 = t & 15, q = t >> 4;
  const int c4 = l16 * 4;
#pragma unroll
  for (int ii = 0; ii < 2; ii++) {
    const int p = q + ii * 16;
    const float4 ra = *(const float4*)&in[(long)(r0 + 2 * p) * in_stride + c0 + c4];
    const float4 rb = *(const float4*)&in[(long)(r0 + 2 * p + 1) * in_stride + c0 + c4];
    tile[c4 + 0][p] = (unsigned)f2b(ra.x) | ((unsigned)f2b(rb.x) << 16);
    tile[c4 + 1][p] = (unsigned)f2b(ra.y) | ((unsigned)f2b(rb.y) << 16);
    tile[c4 + 2][p] = (unsigned)f2b(ra.z) | ((unsigned)f2b(rb.z) << 16);
    tile[c4 + 3][p] = (unsigned)f2b(ra.w) | ((unsigned)f2b(rb.w) << 16);
  }
  __syncthreads();
  const int c = t >> 2, r8 = (t & 3) * 8;
  unsigned v[8];
#pragma unroll
  for (int k = 0; k < 8; k++) v[k] = tile[c][r8 + k];
  uint4 o0 = {v[0], v[1], v[2], v[3]};
  uint4 o1 = {v[4], v[5], v[6], v[7]};
  unsigned short* dst = &out[(long)(c0 + c) * 4096 + r0 + 2 * r8];
  *(uint4*)dst = o0;
  *(uint4*)(dst + 8) = o1;
}

// ---------------- GEMM: C(MxN) = A(MxK) * Bt(NxK)^T, bf16 in, fp32 acc ----------------
// 256x256 tile, BK=64, 512 threads (8 waves, 2Mx4N). ONE-barrier schedule (R10/R12,
// best measured: 119-123us, MfmaUtil 47-50): all 8 global_load_lds for tile t+1
// issue at tile top into nbuf -> zero intra-tile hazards; tile-end vmcnt(0) ~free.
// R13 lesson: fusing QKV into one N=12288 launch was NEUTRAL on gemm time and
// hurt L2 (FETCH 827MB vs 3x147MB) -> keep SEPARATE N=4096 gemms.
// Swizzle: col_elem ^= ((row>>1)&7)<<3 (conflict-free, R5-verified 0 conflicts).
template <int MODE>
__global__ __launch_bounds__(512, 2) void gemm_bt(
    const unsigned short* __restrict__ A,
    const unsigned short* __restrict__ Bt,
    float* __restrict__ Cf,
    unsigned short* __restrict__ Dst,
    int M, int N, int K) {
  __shared__ __align__(16) unsigned short lds[65536];  // 128 KiB
  const int tid = threadIdx.x;
  const int lane = tid & 63;
  const int w = tid >> 6;
  const int quad = lane >> 4, l16 = lane & 15;
  const int wm = w >> 2, wn = w & 3;

  // XCD-aware bijective block swizzle (gridDim.x % 8 == 0)
  const int id = blockIdx.x;
  const int nN = N >> 8;
  const int cpx = (int)gridDim.x >> 3;
  const int swz = (id & 7) * cpx + (id >> 3);
  const int m0 = (swz / nN) * 256;
  const int n0 = (swz % nN) * 256;

  // ---- staging geometry: thread t loads rows lr, lr+64 of a 128-row half, 8 elems at c8 ----
  const int lr = tid >> 3;                 // 0..63
  const int c8 = (tid & 7) * 8;
  const int csw = c8 ^ (((lr >> 1) & 7) << 3);
  const unsigned short* gA = A + (long)(m0 + lr) * K + csw;
  const unsigned short* gB = Bt + (long)(n0 + lr) * K + csw;
  const long K64 = (long)K * 64;           // 64 rows stride
  const int ldsS = lr * 64 + c8;           // linear dest within a half (elems)

  // ---- fragment read offsets (swizzled) ----
  const int fsw = ((l16 >> 1) & 7) << 3;
  const int colk0 = (quad * 8) ^ fsw;
  const int colk1 = colk0 ^ 32;
  const int aoff0 = (wm * 128 + l16) * 64 + colk0;
  const int aoff1 = (wm * 128 + l16) * 64 + colk1;
  const int boff0 = 32768 + (wn * 64 + l16) * 64 + colk0;
  const int boff1 = 32768 + (wn * 64 + l16) * 64 + colk1;

  const f32x4 z4 = {0.f, 0.f, 0.f, 0.f};
  f32x4 acc[8][4];
#pragma unroll
  for (int mi = 0; mi < 8; mi++)
#pragma unroll
    for (int ni = 0; ni < 4; ni++) acc[mi][ni] = z4;

  // ---- prologue: stage tile 0 (A+B, 8 loads) into buf0; drain; barrier ----
  async_cp16(gB, &lds[32768 + ldsS]);
  async_cp16(gB + K64, &lds[32768 + ldsS + 4096]);
  async_cp16(gB + 2 * K64, &lds[32768 + 8192 + ldsS]);
  async_cp16(gB + 3 * K64, &lds[32768 + 8192 + ldsS + 4096]);
  async_cp16(gA, &lds[ldsS]);
  async_cp16(gA + K64, &lds[ldsS + 4096]);
  async_cp16(gA + 2 * K64, &lds[8192 + ldsS]);
  async_cp16(gA + 3 * K64, &lds[8192 + ldsS + 4096]);
  asm volatile("s_waitcnt vmcnt(0)\n\ts_barrier" ::: "memory");

  const int NT = 64;  // K / 64
  for (int t = 0; t < NT; ++t) {
    const int buf = (t & 1) * 16384;
    const int nbuf = 16384 - buf;
    const long kA = (long)(t + 1) * 64;
    s16x8 a1[4][2], a2[4][2], b0[2][2], b1[2][2];

    // ---- stage ALL of tile t+1 (A then B) into nbuf at tile top ----
    if (t < NT - 1) {
      async_cp16(gA + kA, &lds[nbuf + ldsS]);
      async_cp16(gA + kA + K64, &lds[nbuf + ldsS + 4096]);
      async_cp16(gA + kA + 2 * K64, &lds[nbuf + 8192 + ldsS]);
      async_cp16(gA + kA + 3 * K64, &lds[nbuf + 8192 + ldsS + 4096]);
      async_cp16(gB + kA, &lds[32768 + nbuf + ldsS]);
      async_cp16(gB + kA + K64, &lds[32768 + nbuf + ldsS + 4096]);
      async_cp16(gB + kA + 2 * K64, &lds[32768 + nbuf + 8192 + ldsS]);
      async_cp16(gB + kA + 3 * K64, &lds[32768 + nbuf + 8192 + ldsS + 4096]);
    }

    // ---- half 1: read a1(mi0-3) + all B; 32 MFMA ----
#pragma unroll
    for (int mi = 0; mi < 4; ++mi) {
      a1[mi][0] = *(const s16x8*)&lds[buf + aoff0 + mi * 1024];
      a1[mi][1] = *(const s16x8*)&lds[buf + aoff1 + mi * 1024];
    }
#pragma unroll
    for (int ni = 0; ni < 2; ++ni) {
      b0[ni][0] = *(const s16x8*)&lds[buf + boff0 + ni * 1024];
      b0[ni][1] = *(const s16x8*)&lds[buf + boff1 + ni * 1024];
      b1[ni][0] = *(const s16x8*)&lds[buf + boff0 + (ni + 2) * 1024];
      b1[ni][1] = *(const s16x8*)&lds[buf + boff1 + (ni + 2) * 1024];
    }
    __builtin_amdgcn_s_setprio(1);
#pragma unroll
    for (int mi = 0; mi < 4; ++mi)
#pragma unroll
      for (int ni = 0; ni < 2; ++ni) {
        acc[mi][ni] = MFMA16(a1[mi][0], b0[ni][0], acc[mi][ni]);
        acc[mi][ni] = MFMA16(a1[mi][1], b0[ni][1], acc[mi][ni]);
        acc[mi][ni + 2] = MFMA16(a1[mi][0], b1[ni][0], acc[mi][ni + 2]);
        acc[mi][ni + 2] = MFMA16(a1[mi][1], b1[ni][1], acc[mi][ni + 2]);
      }
    __builtin_amdgcn_s_setprio(0);

    // ---- half 2: read a2(mi4-7); 32 MFMA ----
#pragma unroll
    for (int mi = 0; mi < 4; ++mi) {
      a2[mi][0] = *(const s16x8*)&lds[buf + aoff0 + (mi + 4) * 1024];
      a2[mi][1] = *(const s16x8*)&lds[buf + aoff1 + (mi + 4) * 1024];
    }
    __builtin_amdgcn_s_setprio(1);
#pragma unroll
    for (int mi = 0; mi < 4; ++mi)
#pragma unroll
      for (int ni = 0; ni < 2; ++ni) {
        acc[mi + 4][ni] = MFMA16(a2[mi][0], b0[ni][0], acc[mi + 4][ni]);
        acc[mi + 4][ni] = MFMA16(a2[mi][1], b0[ni][1], acc[mi + 4][ni]);
        acc[mi + 4][ni + 2] = MFMA16(a2[mi][0], b1[ni][0], acc[mi + 4][ni + 2]);
        acc[mi + 4][ni + 2] = MFMA16(a2[mi][1], b1[ni][1], acc[mi + 4][ni + 2]);
      }
    __builtin_amdgcn_s_setprio(0);

    // ---- single per-tile sync: t+1 staged a full tile ago -> vmcnt(0) ~free ----
    if (t < NT - 1) {
      asm volatile("s_waitcnt vmcnt(0)\n\ts_barrier" ::: "memory");
    }
  }

  // ---- epilogue ----
#pragma unroll
  for (int mi = 0; mi < 8; ++mi)
#pragma unroll
    for (int ni = 0; ni < 4; ++ni) {
      const int row = m0 + wm * 128 + mi * 16 + quad * 4;
      const int col = n0 + wn * 64 + ni * 16 + l16;
      if (MODE == 0) {
#pragma unroll
        for (int r = 0; r < 4; ++r)
          Cf[(long)(row + r) * N + col] = acc[mi][ni][r];
      } else {
        const int h = col >> 7, d = col & 127;
#pragma unroll
        for (int r = 0; r < 4; ++r) {
          const int m = row + r;
          const int b = m >> 11, s = m & 2047;
          Dst[((long)((b * NH_ + h) * S_) + s) * HD_ + d] = f2b(acc[mi][ni][r]);
        }
      }
    }
}

// ---------------- RoPE (NeoX), vectorized ushort4; Q pre-scaled by 1/sqrt(d)*log2(e) ----------------
__global__ void rope_kernel(unsigned short* __restrict__ Qb,
                            unsigned short* __restrict__ Kb,
                            const int* __restrict__ pos_ids) {
  const float QSCALE = 1.4426950408889634f * 0.08838834764831845f;  // log2(e)/sqrt(128)
  const long idx = (long)blockIdx.x * 256 + threadIdx.x;
  const int i4 = (int)(idx & 15) * 4;
  const long row = idx >> 4;
  const int s = (int)(row & (S_ - 1));
  const int b = (int)(row >> 16);
  const float pos = (float)pos_ids[b * S_ + s];
  const long base = row * HD_;

  ushort4 q1v = *(const ushort4*)&Qb[base + i4];
  ushort4 q2v = *(const ushort4*)&Qb[base + 64 + i4];
  ushort4 k1v = *(const ushort4*)&Kb[base + i4];
  ushort4 k2v = *(const ushort4*)&Kb[base + 64 + i4];
  ushort4 q1o, q2o, k1o, k2o;
  unsigned short* q1p = &q1v.x; unsigned short* q2p = &q2v.x;
  unsigned short* k1p = &k1v.x; unsigned short* k2p = &k2v.x;
  unsigned short* q1q = &q1o.x; unsigned short* q2q = &q2o.x;
  unsigned short* k1q = &k1o.x; unsigned short* k2q = &k2o.x;
#pragma unroll
  for (int e = 0; e < 4; e++) {
    const float inv = exp2f(-(float)(i4 + e) * 0.20762050593046f);
    const float ang = pos * inv;
    const float sn = sinf(ang), cs = cosf(ang);
    const float q1 = b2f(q1p[e]), q2 = b2f(q2p[e]);
    q1q[e] = f2b((q1 * cs - q2 * sn) * QSCALE);
    q2q[e] = f2b((q2 * cs + q1 * sn) * QSCALE);
    const float k1 = b2f(k1p[e]), k2 = b2f(k2p[e]);
    k1q[e] = f2b(k1 * cs - k2 * sn);
    k2q[e] = f2b(k2 * cs + k1 * sn);
  }
  *(ushort4*)&Qb[base + i4] = q1o;
  *(ushort4*)&Qb[base + 64 + i4] = q2o;
  *(ushort4*)&Kb[base + i4] = k1o;
  *(ushort4*)&Kb[base + 64 + i4] = k2o;
}

// ---------------- per-head transpose V (S x HD) -> Vt (HD x S), vectorized ----------------
__global__ void transpose_v(const unsigned short* __restrict__ V,
                            unsigned short* __restrict__ Vt) {
  __shared__ unsigned tile[64][33];  // [d][s_pair]
  const int bh = blockIdx.z;
  const int s0 = blockIdx.x * 64;
  const int d0 = blockIdx.y * 64;
  const unsigned short* src = V + (long)bh * S_ * HD_;
  unsigned short* dst = Vt + (long)bh * S_ * HD_;
  const int t = threadIdx.x;
  const int l16 = t & 15, q = t >> 4;
  const int d4 = l16 * 4;
#pragma unroll
  for (int ii = 0; ii < 2; ii++) {
    const int p = q + ii * 16;
    const ushort4 ra = *(const ushort4*)&src[(long)(s0 + 2 * p) * HD_ + d0 + d4];
    const ushort4 rb = *(const ushort4*)&src[(long)(s0 + 2 * p + 1) * HD_ + d0 + d4];
    tile[d4 + 0][p] = (unsigned)ra.x | ((unsigned)rb.x << 16);
    tile[d4 + 1][p] = (unsigned)ra.y | ((unsigned)rb.y << 16);
    tile[d4 + 2][p] = (unsigned)ra.z | ((unsigned)rb.z << 16);
    tile[d4 + 3][p] = (unsigned)ra.w | ((unsigned)rb.w << 16);
  }
  __syncthreads();
  const int c = t >> 2, r8 = (t & 3) * 8;
  unsigned v[8];
#pragma unroll
  for (int k = 0; k < 8; k++) v[k] = tile[c][r8 + k];
  uint4 o0 = {v[0], v[1], v[2], v[3]};
  uint4 o1 = {v[4], v[5], v[6], v[7]};
  unsigned short* dstp = &dst[(long)(d0 + c) * S_ + s0 + 2 * r8];
  *(uint4*)dstp = o0;
  *(uint4*)(dstp + 8) = o1;
}

// ---------------- flash attention (causal), pipelined K/V staging ----------------
// grid (bh 0..63, qx 0..7): id%8 = bh%8 -> the 8 qx-blocks sharing one head's K/V
// land on the SAME XCD (L2 co-location). Per tile: QK from Ks -> barrier -> issue
// K(t+1)/V(t+1) staging -> softmax+PV from Vs[cur] -> vmcnt(0)+barrier (drain sits
// after ~500cy of compute -> latency hidden). Vs double-buffered.
__global__ __launch_bounds__(256, 2) void flash_attn(
    const unsigned short* __restrict__ Qb,   // (B,NH,S,HD)
    const unsigned short* __restrict__ Kb,   // (B,NH,S,HD)
    const unsigned short* __restrict__ Vt,   // (B,NH,HD,S)
    unsigned short* __restrict__ Ab) {       // (B,S,H) bf16
  __shared__ __align__(16) unsigned short Ks[16 * 64 * 8];       // 16 KB
  __shared__ __align__(16) unsigned short Vs[2][8 * 128 * 8];    // 32 KB
  __shared__ __align__(16) unsigned short plds[128 * 72];        // 18 KB
  const int tid = threadIdx.x;
  const int w = tid >> 6, lane = tid & 63;
  const int quad = lane >> 4, l16 = lane & 15;
  const int qx = blockIdx.y;
  const int bh = blockIdx.x;
  const int b = bh >> 5, h = bh & 31;

  const unsigned short* Qh = Qb + (long)bh * S_ * HD_;
  const unsigned short* Kh = Kb + (long)bh * S_ * HD_;
  const unsigned short* Vh = Vt + (long)bh * S_ * HD_;

  const unsigned short* kstage = Kh + (long)(tid & 63) * HD_ + (tid >> 6) * 8;
  const unsigned short* vstage = Vh + (long)(tid & 127) * S_ + (tid >> 7) * 8;

  const f32x4 z4 = {0.f, 0.f, 0.f, 0.f};
  s16x8 onesv;
#pragma unroll
  for (int j = 0; j < 8; j++) onesv[j] = (short)0x3F80;  // bf16 1.0

  // prologue: stage tile 0 of half 0
#pragma unroll
  for (int j = 0; j < 4; j++)
    async_cp16(kstage + j * 32, &Ks[(j * 256 + tid) * 8]);
#pragma unroll
  for (int j = 0; j < 4; j++)
    async_cp16(vstage + j * 16, &Vs[0][(j * 256 + tid) * 8]);
  asm volatile("s_waitcnt vmcnt(0)" ::: "memory");
  __syncthreads();

  for (int half = 0; half < 2; half++) {
    const int qt = half ? qx : 15 - qx;   // heavy tile first
    const int q0 = qt * 128;
    const int wq = q0 + w * 32;

    s16x8 qf[2][4];
#pragma unroll
    for (int rb = 0; rb < 2; rb++)
#pragma unroll
      for (int ks = 0; ks < 4; ks++)
        qf[rb][ks] = *(const s16x8*)(Qh + (long)(wq + rb * 16 + l16) * HD_ + ks * 32 + quad * 8);

    f32x4 oacc[2][8];
    f32x4 lacc[2];
#pragma unroll
    for (int rb = 0; rb < 2; rb++) {
#pragma unroll
      for (int oc = 0; oc < 8; oc++) oacc[rb][oc] = z4;
      lacc[rb] = z4;
    }
    float mrow[2][4];
#pragma unroll
    for (int rb = 0; rb < 2; rb++)
#pragma unroll
      for (int r = 0; r < 4; r++) mrow[rb][r] = -3.0e38f;

    const int nkt = 2 * qt + 2;   // even

    for (int kt = 0; kt < nkt; kt++) {
      const int kbase = kt * 64;
      const int cur = kt & 1;
      const bool active = (kbase < wq + 32);

      // ---- QK^T: 128 q x 64 k (log2-domain scores) ----
      f32x4 sacc[2][4];
      if (active) {
#pragma unroll
        for (int rb = 0; rb < 2; rb++)
#pragma unroll
          for (int ni = 0; ni < 4; ni++) sacc[rb][ni] = z4;
        __builtin_amdgcn_s_setprio(1);
#pragma unroll
        for (int ni = 0; ni < 4; ni++) {
#pragma unroll
          for (int ks = 0; ks < 4; ks++) {
            const s16x8 kf = *(const s16x8*)&Ks[((ks * 4 + quad) * 64 + ni * 16 + l16) * 8];
            sacc[0][ni] = MFMA16(qf[0][ks], kf, sacc[0][ni]);
            sacc[1][ni] = MFMA16(qf[1][ks], kf, sacc[1][ni]);
          }
        }
        __builtin_amdgcn_s_setprio(0);
      }
      __syncthreads();  // all waves' Ks reads done; Vs[1-cur] free (PV(t-1) complete)

      // ---- issue next tile's staging NOW; latency hides under softmax+PV ----
      const bool more = (kt + 1 < nkt);
      if (more || half == 0) {
        const long nkb = more ? (long)(kbase + 64) : 0;  // half boundary: tile 0 of next half
#pragma unroll
        for (int j = 0; j < 4; j++)
          async_cp16(kstage + nkb * HD_ + j * 32, &Ks[(j * 256 + tid) * 8]);
#pragma unroll
        for (int j = 0; j < 4; j++)
          async_cp16(vstage + nkb + j * 16, &Vs[1 - cur][(j * 256 + tid) * 8]);
      }

      if (active) {
        // ---- mask + per-lane partial max -> defer-max gate (no cross-lane reduce) ----
        const bool band = (kbase + 64 > wq);  // wave-uniform
        float pm[2][4];
        bool small_ = true;
#pragma unroll
        for (int rb = 0; rb < 2; rb++) {
          const int rloc = w * 32 + rb * 16 + quad * 4;
          if (band) {
#pragma unroll
            for (int ni = 0; ni < 4; ni++)
#pragma unroll
              for (int r = 0; r < 4; r++)
                if (kbase + ni * 16 + l16 > q0 + rloc + r) sacc[rb][ni][r] = -3.0e38f;
          }
#pragma unroll
          for (int r = 0; r < 4; r++) {
            pm[rb][r] = fmaxf(fmaxf(sacc[rb][0][r], sacc[rb][1][r]),
                              fmaxf(sacc[rb][2][r], sacc[rb][3][r]));
            small_ = small_ && (pm[rb][r] <= mrow[rb][r] + 8.0f);
          }
        }
        const bool nores = __all(small_);

        if (!nores) {
          // slow path: true row max via shuffle, rescale oacc and lacc
#pragma unroll
          for (int rb = 0; rb < 2; rb++) {
            float alpha[4];
#pragma unroll
            for (int r = 0; r < 4; r++) {
              float m = pm[rb][r];
#pragma unroll
              for (int off = 1; off < 16; off <<= 1) m = fmaxf(m, __shfl_xor(m, off));
              const float mn = fmaxf(mrow[rb][r], m);
              alpha[r] = __builtin_amdgcn_exp2f(mrow[rb][r] - mn);
              mrow[rb][r] = mn;
            }
#pragma unroll
            for (int oc = 0; oc < 8; oc++)
#pragma unroll
              for (int r = 0; r < 4; r++) oacc[rb][oc][r] *= alpha[r];
#pragma unroll
            for (int r = 0; r < 4; r++) lacc[rb][r] *= alpha[r];
          }
        }

        // ---- P = exp2(s - mrow), store to LDS (A-fragment layout) ----
#pragma unroll
        for (int rb = 0; rb < 2; rb++) {
          const int rloc = w * 32 + rb * 16 + quad * 4;
#pragma unroll
          for (int ni = 0; ni < 4; ni++)
#pragma unroll
            for (int r = 0; r < 4; r++) {
              const float p = __builtin_amdgcn_exp2f(sacc[rb][ni][r] - mrow[rb][r]);
              plds[(rloc + r) * 72 + ni * 16 + l16] = f2b_trunc(p);
            }
        }

        // P (A-layout) from LDS: wave reads only rows it wrote -> no barrier needed
        s16x8 af[2][2];
#pragma unroll
        for (int rb = 0; rb < 2; rb++)
#pragma unroll
          for (int ks = 0; ks < 2; ks++)
            af[rb][ks] = *(const s16x8*)&plds[(w * 32 + rb * 16 + l16) * 72 + ks * 32 + quad * 8];
        __builtin_amdgcn_s_setprio(1);
        // row-sum via MFMA with all-ones B: lacc[rb][r] accumulates sum_k P[row][k]
#pragma unroll
        for (int rb = 0; rb < 2; rb++) {
          lacc[rb] = MFMA16(af[rb][0], onesv, lacc[rb]);
          lacc[rb] = MFMA16(af[rb][1], onesv, lacc[rb]);
        }
#pragma unroll
        for (int oc = 0; oc < 8; oc++) {
#pragma unroll
          for (int ks = 0; ks < 2; ks++) {
            const s16x8 vf = *(const s16x8*)&Vs[cur][((ks * 4 + quad) * 128 + oc * 16 + l16) * 8];
            oacc[0][oc] = MFMA16(af[0][ks], vf, oacc[0][oc]);
            oacc[1][oc] = MFMA16(af[1][ks], vf, oacc[1][oc]);
          }
        }
        __builtin_amdgcn_s_setprio(0);
      }

      // ---- drain staged loads (mostly complete by now) + publish ----
      asm volatile("s_waitcnt vmcnt(0)" ::: "memory");
      __syncthreads();
    }

#pragma unroll
    for (int rb = 0; rb < 2; rb++) {
      float inv_l[4];
#pragma unroll
      for (int r = 0; r < 4; r++) inv_l[r] = 1.f / lacc[rb][r];
#pragma unroll
      for (int oc = 0; oc < 8; oc++)
#pragma unroll
        for (int r = 0; r < 4; r++) {
          const int s = q0 + w * 32 + rb * 16 + quad * 4 + r;
          const int d = oc * 16 + l16;
          Ab[((long)(b * S_ + s)) * H_ + h * HD_ + d] = f2b(oacc[rb][oc][r] * inv_l[r]);
        }
    }
  }
}

extern "C" void kernel_launch(void* const* d_in, const int* in_sizes, int n_in,
                              void* d_out, int out_size, void* d_ws, size_t ws_size,
                              hipStream_t stream) {
  const float* hs = (const float*)d_in[0];
  const float* w_qkv = (const float*)d_in[1];
  const float* w_o = (const float*)d_in[2];
  const int* pos = (const int*)d_in[3];
  float* out = (float*)d_out;

  unsigned short* Xb = (unsigned short*)d_ws;
  unsigned short* Wt = Xb + EL_;            // 3*EL for fused QKV weight transpose
  unsigned short* Qb = Wt + 3 * EL_;
  unsigned short* Kb = Qb + EL_;
  unsigned short* Vb = Kb + EL_;
  unsigned short* Vt = Vb + EL_;
  unsigned short* Ab = Xb;                  // alias: Xb dead after QKV GEMMs

  cast_f32_bf16<<<(EL_ / 4 + 255) / 256, 256, 0, stream>>>(hs, Xb, EL_);

  // one fused weight transpose (removes tcast<->gemm alternation), then 3
  // separate N=4096 gemms back-to-back (R13: fused N=12288 gemm hurt L2).
  transpose_cast_4096<<<dim3(192, 64), 256, 0, stream>>>(w_qkv, Wt, 12288);
  unsigned short* qkv_dst[3] = {Qb, Kb, Vb};
  for (int p = 0; p < 3; p++)
    gemm_bt<1><<<dim3(256), dim3(512), 0, stream>>>(Xb, Wt + p * EL_, nullptr, qkv_dst[p], 4096, 4096, 4096);

  rope_kernel<<<(B_ * NH_ * S_ * 16) / 256, 256, 0, stream>>>(Qb, Kb, pos);
  transpose_v<<<dim3(32, 2, 64), 256, 0, stream>>>(Vb, Vt);
  flash_attn<<<dim3(64, 8), 256, 0, stream>>>(Qb, Kb, Vt, Ab);

  transpose_cast_4096<<<dim3(64, 64), 256, 0, stream>>>(w_o, Wt, 4096);
  gemm_bt<0><<<dim3(256), dim3(512), 0, stream>>>(Ab, Wt, out, nullptr, 4096, 4096, 4096);
}

// Round 15
// 931.417 us; speedup vs baseline: 1.0222x; 1.0222x over previous
//
#include <hip/hip_runtime.h>
#include <stdint.h>
#include <math.h>

#define B_ 2
#define S_ 2048
#define H_ 4096
#define NH_ 32
#define HD_ 128

using s16x8 = __attribute__((ext_vector_type(8))) short;
using f32x4 = __attribute__((ext_vector_type(4))) float;

__device__ __forceinline__ unsigned short f2b(float f) {
  union { float f; unsigned u; } v; v.f = f;
  unsigned r = v.u + 0x7FFFu + ((v.u >> 16) & 1u);
  return (unsigned short)(r >> 16);
}
__device__ __forceinline__ unsigned short f2b_trunc(float f) {
  union { float f; unsigned u; } v; v.f = f;
  return (unsigned short)(v.u >> 16);
}
__device__ __forceinline__ float b2f(unsigned short h) {
  union { unsigned u; float f; } v; v.u = ((unsigned)h) << 16;
  return v.f;
}

__device__ __forceinline__ void async_cp16(const void* g, void* l) {
  __builtin_amdgcn_global_load_lds(
      (__attribute__((address_space(1))) void*)(void*)g,
      (__attribute__((address_space(3))) void*)l, 16, 0, 0);
}

#define MFMA16(a, b, c) __builtin_amdgcn_mfma_f32_16x16x32_bf16((a), (b), (c), 0, 0, 0)
#define BARRIER() asm volatile("s_barrier" ::: "memory")

// ---------------- cast fp32 -> bf16 ----------------
__global__ void cast_f32_bf16(const float* __restrict__ in,
                              unsigned short* __restrict__ out, long n) {
  long i = ((long)blockIdx.x * 256 + threadIdx.x) * 4;
  if (i >= n) return;
  const float4 v = *(const float4*)(in + i);
  ushort4 o;
  o.x = f2b(v.x); o.y = f2b(v.y); o.z = f2b(v.z); o.w = f2b(v.w);
  *(ushort4*)(out + i) = o;
}

// ------- transpose+cast (vectorized): in (rows x in_stride fp32) -> out 4096x4096 bf16 transposed -------
__global__ void transpose_cast_4096(const float* __restrict__ in,
                                    unsigned short* __restrict__ out, int in_stride) {
  __shared__ unsigned tile[64][33];  // [out_row c][row_pair p]: lo=bf16(2p), hi=bf16(2p+1)
  const int t = threadIdx.x;
  const int c0 = blockIdx.x * 64;
  const int r0 = blockIdx.y * 64;
  const int l16 = t & 15, q = t >> 4;
  const int c4 = l16 * 4;
#pragma unroll
  for (int ii = 0; ii < 2; ii++) {
    const int p = q + ii * 16;
    const float4 ra = *(const float4*)&in[(long)(r0 + 2 * p) * in_stride + c0 + c4];
    const float4 rb = *(const float4*)&in[(long)(r0 + 2 * p + 1) * in_stride + c0 + c4];
    tile[c4 + 0][p] = (unsigned)f2b(ra.x) | ((unsigned)f2b(rb.x) << 16);
    tile[c4 + 1][p] = (unsigned)f2b(ra.y) | ((unsigned)f2b(rb.y) << 16);
    tile[c4 + 2][p] = (unsigned)f2b(ra.z) | ((unsigned)f2b(rb.z) << 16);
    tile[c4 + 3][p] = (unsigned)f2b(ra.w) | ((unsigned)f2b(rb.w) << 16);
  }
  __syncthreads();
  const int c = t >> 2, r8 = (t & 3) * 8;
  unsigned v[8];
#pragma unroll
  for (int k = 0; k < 8; k++) v[k] = tile[c][r8 + k];
  uint4 o0 = {v[0], v[1], v[2], v[3]};
  uint4 o1 = {v[4], v[5], v[6], v[7]};
  unsigned short* dst = &out[(long)(c0 + c) * 4096 + r0 + 2 * r8];
  *(uint4*)dst = o0;
  *(uint4*)(dst + 8) = o1;
}

// ---------------- GEMM: C(MxN) = A(MxK) * Bt(NxK)^T, bf16 in, fp32 acc ----------------
// 256x256 tile, BK=64, 512 threads (8 waves, 2Mx4N). ONE-barrier schedule (R10/R12,
// best measured: 119-123us, MfmaUtil 47-50): all 8 global_load_lds for tile t+1
// issue at tile top into nbuf (nobody reads it this tile) -> zero intra-tile
// hazards. Tile-end vmcnt(0) ~free (loads issued a full tile ~4400cy ago >> 900cy
// HBM latency). R11: LDS=128KB -> ONE block/CU; regs cap 2 waves/SIMD -> ~50%
// MfmaUtil is this structure's ceiling. R13: N=12288 fusion neutral, hurt L2.
// R14: pre-transposing all QKV weights hurt L2 (~10us) -> keep per-slice interleave.
// Swizzle: col_elem ^= ((row>>1)&7)<<3 (conflict-free, R5-verified 0 conflicts).
template <int MODE>
__global__ __launch_bounds__(512, 2) void gemm_bt(
    const unsigned short* __restrict__ A,
    const unsigned short* __restrict__ Bt,
    float* __restrict__ Cf,
    unsigned short* __restrict__ Dst,
    int M, int N, int K) {
  __shared__ __align__(16) unsigned short lds[65536];  // 128 KiB
  const int tid = threadIdx.x;
  const int lane = tid & 63;
  const int w = tid >> 6;
  const int quad = lane >> 4, l16 = lane & 15;
  const int wm = w >> 2, wn = w & 3;

  // XCD-aware bijective block swizzle (256 blocks, 256 % 8 == 0)
  const int id = blockIdx.x;
  const int swz = (id & 7) * 32 + (id >> 3);
  const int m0 = (swz >> 4) * 256;
  const int n0 = (swz & 15) * 256;

  // ---- staging geometry: thread t loads rows lr, lr+64 of a 128-row half, 8 elems at c8 ----
  const int lr = tid >> 3;                 // 0..63
  const int c8 = (tid & 7) * 8;
  const int csw = c8 ^ (((lr >> 1) & 7) << 3);
  const unsigned short* gA = A + (long)(m0 + lr) * K + csw;
  const unsigned short* gB = Bt + (long)(n0 + lr) * K + csw;
  const long K64 = (long)K * 64;           // 64 rows stride
  const int ldsS = lr * 64 + c8;           // linear dest within a half (elems)

  // ---- fragment read offsets (swizzled) ----
  const int fsw = ((l16 >> 1) & 7) << 3;
  const int colk0 = (quad * 8) ^ fsw;
  const int colk1 = colk0 ^ 32;
  const int aoff0 = (wm * 128 + l16) * 64 + colk0;
  const int aoff1 = (wm * 128 + l16) * 64 + colk1;
  const int boff0 = 32768 + (wn * 64 + l16) * 64 + colk0;
  const int boff1 = 32768 + (wn * 64 + l16) * 64 + colk1;

  const f32x4 z4 = {0.f, 0.f, 0.f, 0.f};
  f32x4 acc[8][4];
#pragma unroll
  for (int mi = 0; mi < 8; mi++)
#pragma unroll
    for (int ni = 0; ni < 4; ni++) acc[mi][ni] = z4;

  // ---- prologue: stage tile 0 (A+B, 8 loads) into buf0; drain; barrier ----
  async_cp16(gB, &lds[32768 + ldsS]);
  async_cp16(gB + K64, &lds[32768 + ldsS + 4096]);
  async_cp16(gB + 2 * K64, &lds[32768 + 8192 + ldsS]);
  async_cp16(gB + 3 * K64, &lds[32768 + 8192 + ldsS + 4096]);
  async_cp16(gA, &lds[ldsS]);
  async_cp16(gA + K64, &lds[ldsS + 4096]);
  async_cp16(gA + 2 * K64, &lds[8192 + ldsS]);
  async_cp16(gA + 3 * K64, &lds[8192 + ldsS + 4096]);
  asm volatile("s_waitcnt vmcnt(0)\n\ts_barrier" ::: "memory");

  const int NT = 64;  // K / 64
  for (int t = 0; t < NT; ++t) {
    const int buf = (t & 1) * 16384;
    const int nbuf = 16384 - buf;
    const long kA = (long)(t + 1) * 64;
    s16x8 a1[4][2], a2[4][2], b0[2][2], b1[2][2];

    // ---- stage ALL of tile t+1 (A then B) into nbuf at tile top ----
    if (t < NT - 1) {
      async_cp16(gA + kA, &lds[nbuf + ldsS]);
      async_cp16(gA + kA + K64, &lds[nbuf + ldsS + 4096]);
      async_cp16(gA + kA + 2 * K64, &lds[nbuf + 8192 + ldsS]);
      async_cp16(gA + kA + 3 * K64, &lds[nbuf + 8192 + ldsS + 4096]);
      async_cp16(gB + kA, &lds[32768 + nbuf + ldsS]);
      async_cp16(gB + kA + K64, &lds[32768 + nbuf + ldsS + 4096]);
      async_cp16(gB + kA + 2 * K64, &lds[32768 + nbuf + 8192 + ldsS]);
      async_cp16(gB + kA + 3 * K64, &lds[32768 + nbuf + 8192 + ldsS + 4096]);
    }

    // ---- half 1: read a1(mi0-3) + all B; 32 MFMA ----
#pragma unroll
    for (int mi = 0; mi < 4; ++mi) {
      a1[mi][0] = *(const s16x8*)&lds[buf + aoff0 + mi * 1024];
      a1[mi][1] = *(const s16x8*)&lds[buf + aoff1 + mi * 1024];
    }
#pragma unroll
    for (int ni = 0; ni < 2; ++ni) {
      b0[ni][0] = *(const s16x8*)&lds[buf + boff0 + ni * 1024];
      b0[ni][1] = *(const s16x8*)&lds[buf + boff1 + ni * 1024];
      b1[ni][0] = *(const s16x8*)&lds[buf + boff0 + (ni + 2) * 1024];
      b1[ni][1] = *(const s16x8*)&lds[buf + boff1 + (ni + 2) * 1024];
    }
    __builtin_amdgcn_s_setprio(1);
#pragma unroll
    for (int mi = 0; mi < 4; ++mi)
#pragma unroll
      for (int ni = 0; ni < 2; ++ni) {
        acc[mi][ni] = MFMA16(a1[mi][0], b0[ni][0], acc[mi][ni]);
        acc[mi][ni] = MFMA16(a1[mi][1], b0[ni][1], acc[mi][ni]);
        acc[mi][ni + 2] = MFMA16(a1[mi][0], b1[ni][0], acc[mi][ni + 2]);
        acc[mi][ni + 2] = MFMA16(a1[mi][1], b1[ni][1], acc[mi][ni + 2]);
      }
    __builtin_amdgcn_s_setprio(0);

    // ---- half 2: read a2(mi4-7); 32 MFMA ----
#pragma unroll
    for (int mi = 0; mi < 4; ++mi) {
      a2[mi][0] = *(const s16x8*)&lds[buf + aoff0 + (mi + 4) * 1024];
      a2[mi][1] = *(const s16x8*)&lds[buf + aoff1 + (mi + 4) * 1024];
    }
    __builtin_amdgcn_s_setprio(1);
#pragma unroll
    for (int mi = 0; mi < 4; ++mi)
#pragma unroll
      for (int ni = 0; ni < 2; ++ni) {
        acc[mi + 4][ni] = MFMA16(a2[mi][0], b0[ni][0], acc[mi + 4][ni]);
        acc[mi + 4][ni] = MFMA16(a2[mi][1], b0[ni][1], acc[mi + 4][ni]);
        acc[mi + 4][ni + 2] = MFMA16(a2[mi][0], b1[ni][0], acc[mi + 4][ni + 2]);
        acc[mi + 4][ni + 2] = MFMA16(a2[mi][1], b1[ni][1], acc[mi + 4][ni + 2]);
      }
    __builtin_amdgcn_s_setprio(0);

    // ---- single per-tile sync: t+1 staged a full tile ago -> vmcnt(0) ~free ----
    if (t < NT - 1) {
      asm volatile("s_waitcnt vmcnt(0)\n\ts_barrier" ::: "memory");
    }
  }

  // ---- epilogue ----
#pragma unroll
  for (int mi = 0; mi < 8; ++mi)
#pragma unroll
    for (int ni = 0; ni < 4; ++ni) {
      const int row = m0 + wm * 128 + mi * 16 + quad * 4;
      const int col = n0 + wn * 64 + ni * 16 + l16;
      if (MODE == 0) {
#pragma unroll
        for (int r = 0; r < 4; ++r)
          Cf[(long)(row + r) * N + col] = acc[mi][ni][r];
      } else {
        const int h = col >> 7, d = col & 127;
#pragma unroll
        for (int r = 0; r < 4; ++r) {
          const int m = row + r;
          const int b = m >> 11, s = m & 2047;
          Dst[((long)((b * NH_ + h) * S_) + s) * HD_ + d] = f2b(acc[mi][ni][r]);
        }
      }
    }
}

// ---------------- RoPE (NeoX), vectorized ushort4; Q pre-scaled by 1/sqrt(d)*log2(e) ----------------
__global__ void rope_kernel(unsigned short* __restrict__ Qb,
                            unsigned short* __restrict__ Kb,
                            const int* __restrict__ pos_ids) {
  const float QSCALE = 1.4426950408889634f * 0.08838834764831845f;  // log2(e)/sqrt(128)
  const long idx = (long)blockIdx.x * 256 + threadIdx.x;
  const int i4 = (int)(idx & 15) * 4;
  const long row = idx >> 4;
  const int s = (int)(row & (S_ - 1));
  const int b = (int)(row >> 16);
  const float pos = (float)pos_ids[b * S_ + s];
  const long base = row * HD_;

  ushort4 q1v = *(const ushort4*)&Qb[base + i4];
  ushort4 q2v = *(const ushort4*)&Qb[base + 64 + i4];
  ushort4 k1v = *(const ushort4*)&Kb[base + i4];
  ushort4 k2v = *(const ushort4*)&Kb[base + 64 + i4];
  ushort4 q1o, q2o, k1o, k2o;
  unsigned short* q1p = &q1v.x; unsigned short* q2p = &q2v.x;
  unsigned short* k1p = &k1v.x; unsigned short* k2p = &k2v.x;
  unsigned short* q1q = &q1o.x; unsigned short* q2q = &q2o.x;
  unsigned short* k1q = &k1o.x; unsigned short* k2q = &k2o.x;
#pragma unroll
  for (int e = 0; e < 4; e++) {
    const float inv = exp2f(-(float)(i4 + e) * 0.20762050593046f);
    const float ang = pos * inv;
    const float sn = sinf(ang), cs = cosf(ang);
    const float q1 = b2f(q1p[e]), q2 = b2f(q2p[e]);
    q1q[e] = f2b((q1 * cs - q2 * sn) * QSCALE);
    q2q[e] = f2b((q2 * cs + q1 * sn) * QSCALE);
    const float k1 = b2f(k1p[e]), k2 = b2f(k2p[e]);
    k1q[e] = f2b(k1 * cs - k2 * sn);
    k2q[e] = f2b(k2 * cs + k1 * sn);
  }
  *(ushort4*)&Qb[base + i4] = q1o;
  *(ushort4*)&Qb[base + 64 + i4] = q2o;
  *(ushort4*)&Kb[base + i4] = k1o;
  *(ushort4*)&Kb[base + 64 + i4] = k2o;
}

// ---------------- per-head transpose V (S x HD) -> Vt (HD x S), vectorized ----------------
__global__ void transpose_v(const unsigned short* __restrict__ V,
                            unsigned short* __restrict__ Vt) {
  __shared__ unsigned tile[64][33];  // [d][s_pair]
  const int bh = blockIdx.z;
  const int s0 = blockIdx.x * 64;
  const int d0 = blockIdx.y * 64;
  const unsigned short* src = V + (long)bh * S_ * HD_;
  unsigned short* dst = Vt + (long)bh * S_ * HD_;
  const int t = threadIdx.x;
  const int l16 = t & 15, q = t >> 4;
  const int d4 = l16 * 4;
#pragma unroll
  for (int ii = 0; ii < 2; ii++) {
    const int p = q + ii * 16;
    const ushort4 ra = *(const ushort4*)&src[(long)(s0 + 2 * p) * HD_ + d0 + d4];
    const ushort4 rb = *(const ushort4*)&src[(long)(s0 + 2 * p + 1) * HD_ + d0 + d4];
    tile[d4 + 0][p] = (unsigned)ra.x | ((unsigned)rb.x << 16);
    tile[d4 + 1][p] = (unsigned)ra.y | ((unsigned)rb.y << 16);
    tile[d4 + 2][p] = (unsigned)ra.z | ((unsigned)rb.z << 16);
    tile[d4 + 3][p] = (unsigned)ra.w | ((unsigned)rb.w << 16);
  }
  __syncthreads();
  const int c = t >> 2, r8 = (t & 3) * 8;
  unsigned v[8];
#pragma unroll
  for (int k = 0; k < 8; k++) v[k] = tile[c][r8 + k];
  uint4 o0 = {v[0], v[1], v[2], v[3]};
  uint4 o1 = {v[4], v[5], v[6], v[7]};
  unsigned short* dstp = &dst[(long)(d0 + c) * S_ + s0 + 2 * r8];
  *(uint4*)dstp = o0;
  *(uint4*)(dstp + 8) = o1;
}

// ---------------- flash attention (causal), pipelined K/V staging ----------------
// grid (bh 0..63, qx 0..7): id%8 = bh%8 -> the 8 qx-blocks sharing one head's K/V
// land on the SAME XCD (L2 co-location). Per tile: QK from Ks -> barrier -> issue
// K(t+1)/V(t+1) staging -> softmax+PV from Vs[cur] -> vmcnt(0)+barrier (drain sits
// after ~500cy of compute -> latency hidden). Vs double-buffered.
__global__ __launch_bounds__(256, 2) void flash_attn(
    const unsigned short* __restrict__ Qb,   // (B,NH,S,HD)
    const unsigned short* __restrict__ Kb,   // (B,NH,S,HD)
    const unsigned short* __restrict__ Vt,   // (B,NH,HD,S)
    unsigned short* __restrict__ Ab) {       // (B,S,H) bf16
  __shared__ __align__(16) unsigned short Ks[16 * 64 * 8];       // 16 KB
  __shared__ __align__(16) unsigned short Vs[2][8 * 128 * 8];    // 32 KB
  __shared__ __align__(16) unsigned short plds[128 * 72];        // 18 KB
  const int tid = threadIdx.x;
  const int w = tid >> 6, lane = tid & 63;
  const int quad = lane >> 4, l16 = lane & 15;
  const int qx = blockIdx.y;
  const int bh = blockIdx.x;
  const int b = bh >> 5, h = bh & 31;

  const unsigned short* Qh = Qb + (long)bh * S_ * HD_;
  const unsigned short* Kh = Kb + (long)bh * S_ * HD_;
  const unsigned short* Vh = Vt + (long)bh * S_ * HD_;

  const unsigned short* kstage = Kh + (long)(tid & 63) * HD_ + (tid >> 6) * 8;
  const unsigned short* vstage = Vh + (long)(tid & 127) * S_ + (tid >> 7) * 8;

  const f32x4 z4 = {0.f, 0.f, 0.f, 0.f};
  s16x8 onesv;
#pragma unroll
  for (int j = 0; j < 8; j++) onesv[j] = (short)0x3F80;  // bf16 1.0

  // prologue: stage tile 0 of half 0
#pragma unroll
  for (int j = 0; j < 4; j++)
    async_cp16(kstage + j * 32, &Ks[(j * 256 + tid) * 8]);
#pragma unroll
  for (int j = 0; j < 4; j++)
    async_cp16(vstage + j * 16, &Vs[0][(j * 256 + tid) * 8]);
  asm volatile("s_waitcnt vmcnt(0)" ::: "memory");
  __syncthreads();

  for (int half = 0; half < 2; half++) {
    const int qt = half ? qx : 15 - qx;   // heavy tile first
    const int q0 = qt * 128;
    const int wq = q0 + w * 32;

    s16x8 qf[2][4];
#pragma unroll
    for (int rb = 0; rb < 2; rb++)
#pragma unroll
      for (int ks = 0; ks < 4; ks++)
        qf[rb][ks] = *(const s16x8*)(Qh + (long)(wq + rb * 16 + l16) * HD_ + ks * 32 + quad * 8);

    f32x4 oacc[2][8];
    f32x4 lacc[2];
#pragma unroll
    for (int rb = 0; rb < 2; rb++) {
#pragma unroll
      for (int oc = 0; oc < 8; oc++) oacc[rb][oc] = z4;
      lacc[rb] = z4;
    }
    float mrow[2][4];
#pragma unroll
    for (int rb = 0; rb < 2; rb++)
#pragma unroll
      for (int r = 0; r < 4; r++) mrow[rb][r] = -3.0e38f;

    const int nkt = 2 * qt + 2;   // even

    for (int kt = 0; kt < nkt; kt++) {
      const int kbase = kt * 64;
      const int cur = kt & 1;
      const bool active = (kbase < wq + 32);

      // ---- QK^T: 128 q x 64 k (log2-domain scores) ----
      f32x4 sacc[2][4];
      if (active) {
#pragma unroll
        for (int rb = 0; rb < 2; rb++)
#pragma unroll
          for (int ni = 0; ni < 4; ni++) sacc[rb][ni] = z4;
        __builtin_amdgcn_s_setprio(1);
#pragma unroll
        for (int ni = 0; ni < 4; ni++) {
#pragma unroll
          for (int ks = 0; ks < 4; ks++) {
            const s16x8 kf = *(const s16x8*)&Ks[((ks * 4 + quad) * 64 + ni * 16 + l16) * 8];
            sacc[0][ni] = MFMA16(qf[0][ks], kf, sacc[0][ni]);
            sacc[1][ni] = MFMA16(qf[1][ks], kf, sacc[1][ni]);
          }
        }
        __builtin_amdgcn_s_setprio(0);
      }
      __syncthreads();  // all waves' Ks reads done; Vs[1-cur] free (PV(t-1) complete)

      // ---- issue next tile's staging NOW; latency hides under softmax+PV ----
      const bool more = (kt + 1 < nkt);
      if (more || half == 0) {
        const long nkb = more ? (long)(kbase + 64) : 0;  // half boundary: tile 0 of next half
#pragma unroll
        for (int j = 0; j < 4; j++)
          async_cp16(kstage + nkb * HD_ + j * 32, &Ks[(j * 256 + tid) * 8]);
#pragma unroll
        for (int j = 0; j < 4; j++)
          async_cp16(vstage + nkb + j * 16, &Vs[1 - cur][(j * 256 + tid) * 8]);
      }

      if (active) {
        // ---- mask + per-lane partial max -> defer-max gate (no cross-lane reduce) ----
        const bool band = (kbase + 64 > wq);  // wave-uniform
        float pm[2][4];
        bool small_ = true;
#pragma unroll
        for (int rb = 0; rb < 2; rb++) {
          const int rloc = w * 32 + rb * 16 + quad * 4;
          if (band) {
#pragma unroll
            for (int ni = 0; ni < 4; ni++)
#pragma unroll
              for (int r = 0; r < 4; r++)
                if (kbase + ni * 16 + l16 > q0 + rloc + r) sacc[rb][ni][r] = -3.0e38f;
          }
#pragma unroll
          for (int r = 0; r < 4; r++) {
            pm[rb][r] = fmaxf(fmaxf(sacc[rb][0][r], sacc[rb][1][r]),
                              fmaxf(sacc[rb][2][r], sacc[rb][3][r]));
            small_ = small_ && (pm[rb][r] <= mrow[rb][r] + 8.0f);
          }
        }
        const bool nores = __all(small_);

        if (!nores) {
          // slow path: true row max via shuffle, rescale oacc and lacc
#pragma unroll
          for (int rb = 0; rb < 2; rb++) {
            float alpha[4];
#pragma unroll
            for (int r = 0; r < 4; r++) {
              float m = pm[rb][r];
#pragma unroll
              for (int off = 1; off < 16; off <<= 1) m = fmaxf(m, __shfl_xor(m, off));
              const float mn = fmaxf(mrow[rb][r], m);
              alpha[r] = __builtin_amdgcn_exp2f(mrow[rb][r] - mn);
              mrow[rb][r] = mn;
            }
#pragma unroll
            for (int oc = 0; oc < 8; oc++)
#pragma unroll
              for (int r = 0; r < 4; r++) oacc[rb][oc][r] *= alpha[r];
#pragma unroll
            for (int r = 0; r < 4; r++) lacc[rb][r] *= alpha[r];
          }
        }

        // ---- P = exp2(s - mrow), store to LDS (A-fragment layout) ----
#pragma unroll
        for (int rb = 0; rb < 2; rb++) {
          const int rloc = w * 32 + rb * 16 + quad * 4;
#pragma unroll
          for (int ni = 0; ni < 4; ni++)
#pragma unroll
            for (int r = 0; r < 4; r++) {
              const float p = __builtin_amdgcn_exp2f(sacc[rb][ni][r] - mrow[rb][r]);
              plds[(rloc + r) * 72 + ni * 16 + l16] = f2b_trunc(p);
            }
        }

        // P (A-layout) from LDS: wave reads only rows it wrote -> no barrier needed
        s16x8 af[2][2];
#pragma unroll
        for (int rb = 0; rb < 2; rb++)
#pragma unroll
          for (int ks = 0; ks < 2; ks++)
            af[rb][ks] = *(const s16x8*)&plds[(w * 32 + rb * 16 + l16) * 72 + ks * 32 + quad * 8];
        __builtin_amdgcn_s_setprio(1);
        // row-sum via MFMA with all-ones B: lacc[rb][r] accumulates sum_k P[row][k]
#pragma unroll
        for (int rb = 0; rb < 2; rb++) {
          lacc[rb] = MFMA16(af[rb][0], onesv, lacc[rb]);
          lacc[rb] = MFMA16(af[rb][1], onesv, lacc[rb]);
        }
#pragma unroll
        for (int oc = 0; oc < 8; oc++) {
#pragma unroll
          for (int ks = 0; ks < 2; ks++) {
            const s16x8 vf = *(const s16x8*)&Vs[cur][((ks * 4 + quad) * 128 + oc * 16 + l16) * 8];
            oacc[0][oc] = MFMA16(af[0][ks], vf, oacc[0][oc]);
            oacc[1][oc] = MFMA16(af[1][ks], vf, oacc[1][oc]);
          }
        }
        __builtin_amdgcn_s_setprio(0);
      }

      // ---- drain staged loads (mostly complete by now) + publish ----
      asm volatile("s_waitcnt vmcnt(0)" ::: "memory");
      __syncthreads();
    }

#pragma unroll
    for (int rb = 0; rb < 2; rb++) {
      float inv_l[4];
#pragma unroll
      for (int r = 0; r < 4; r++) inv_l[r] = 1.f / lacc[rb][r];
#pragma unroll
      for (int oc = 0; oc < 8; oc++)
#pragma unroll
        for (int r = 0; r < 4; r++) {
          const int s = q0 + w * 32 + rb * 16 + quad * 4 + r;
          const int d = oc * 16 + l16;
          Ab[((long)(b * S_ + s)) * H_ + h * HD_ + d] = f2b(oacc[rb][oc][r] * inv_l[r]);
        }
    }
  }
}

extern "C" void kernel_launch(void* const* d_in, const int* in_sizes, int n_in,
                              void* d_out, int out_size, void* d_ws, size_t ws_size,
                              hipStream_t stream) {
  const float* hs = (const float*)d_in[0];
  const float* w_qkv = (const float*)d_in[1];
  const float* w_o = (const float*)d_in[2];
  const int* pos = (const int*)d_in[3];
  float* out = (float*)d_out;

  const long EL = (long)4096 * 4096;
  unsigned short* Xb = (unsigned short*)d_ws;
  unsigned short* Wt = Xb + EL;
  unsigned short* Qb = Wt + EL;
  unsigned short* Kb = Qb + EL;
  unsigned short* Vb = Kb + EL;
  unsigned short* Vt = Vb + EL;
  unsigned short* Ab = Xb;  // alias: Xb dead after third QKV GEMM

  cast_f32_bf16<<<(EL / 4 + 255) / 256, 256, 0, stream>>>(hs, Xb, EL);

  unsigned short* qkv_dst[3] = {Qb, Kb, Vb};
  for (int p = 0; p < 3; p++) {
    transpose_cast_4096<<<dim3(64, 64), 256, 0, stream>>>(w_qkv + p * 4096, Wt, 12288);
    gemm_bt<1><<<dim3(256), dim3(512), 0, stream>>>(Xb, Wt, nullptr, qkv_dst[p], 4096, 4096, 4096);
  }

  rope_kernel<<<(B_ * NH_ * S_ * 16) / 256, 256, 0, stream>>>(Qb, Kb, pos);
  transpose_v<<<dim3(32, 2, 64), 256, 0, stream>>>(Vb, Vt);
  flash_attn<<<dim3(64, 8), 256, 0, stream>>>(Qb, Kb, Vt, Ab);

  transpose_cast_4096<<<dim3(64, 64), 256, 0, stream>>>(w_o, Wt, 4096);
  gemm_bt<0><<<dim3(256), dim3(512), 0, stream>>>(Ab, Wt, out, nullptr, 4096, 4096, 4096);
}